// Round 2
// baseline (625.519 us; speedup 1.0000x reference)
//
#include <hip/hip_runtime.h>
#include <hip/hip_fp16.h>

typedef _Float16 half8 __attribute__((ext_vector_type(8)));
typedef float f32x4 __attribute__((ext_vector_type(4)));

static constexpr int B_ = 8, T_ = 64, N_ = 256;
static constexpr int F0 = 12, F1 = 64, F2 = 32;
static constexpr int BT_ = B_ * T_;

__device__ inline float tanh_fast(float x) {
    x = fminf(20.f, fmaxf(-20.f, x));
    float e = __expf(2.f * x);
    return (e - 1.f) / (e + 1.f);
}

// ---------------- K0a: S (BT,256,256) f32 -> S^T hi/lo fp16 planes ----------
// STh/STl[bt][n][m] = split(S[bt][m][n]); contraction index m is contiguous.
__global__ void k_transpose_s(const float* __restrict__ S,
                              _Float16* __restrict__ STh, _Float16* __restrict__ STl) {
    int bt = blockIdx.x;
    const float* s = S + (size_t)bt * N_ * N_;
    _Float16* sth = STh + (size_t)bt * N_ * N_;
    _Float16* stl = STl + (size_t)bt * N_ * N_;
    __shared__ float tile[32][33];
    int tx = threadIdx.x & 31;
    int ty = threadIdx.x >> 5;  // 0..7
    for (int tm = 0; tm < N_; tm += 32) {
        for (int tn = 0; tn < N_; tn += 32) {
            #pragma unroll
            for (int r = ty; r < 32; r += 8)
                tile[r][tx] = s[(size_t)(tm + r) * N_ + tn + tx];
            __syncthreads();
            #pragma unroll
            for (int r = ty; r < 32; r += 8) {
                float v = tile[tx][r];
                _Float16 h = (_Float16)v;
                size_t idx = (size_t)(tn + r) * N_ + tm + tx;
                sth[idx] = h;
                stl[idx] = (_Float16)(v - (float)h);
            }
            __syncthreads();
        }
    }
}

// ---------------- K0b: x (BT,12,256) f32 -> hi/lo fp16 (BT,16,256), rows 12..15 = 0
__global__ void k_convert_x(const float* __restrict__ x,
                            _Float16* __restrict__ xh, _Float16* __restrict__ xl, int total) {
    int i = blockIdx.x * blockDim.x + threadIdx.x;
    if (i >= total) return;
    int n = i & 255;
    int g = (i >> 8) & 15;
    int bt = i >> 12;
    float v = (g < F0) ? x[((size_t)bt * F0 + g) * N_ + n] : 0.0f;
    _Float16 h = (_Float16)v;
    xh[i] = h;
    xl[i] = (_Float16)(v - (float)h);
}

// ---------------- chain matmul: Out(b,t) = Aprev(b,t-1) @ S(b,t), split-fp16 --
template <int MT>
__global__ void k_chain(const _Float16* __restrict__ Ah, const _Float16* __restrict__ Al,
                        const _Float16* __restrict__ STh, const _Float16* __restrict__ STl,
                        _Float16* __restrict__ Oh, _Float16* __restrict__ Ol) {
    constexpr int M = 16 * MT;
    int bt = blockIdx.x;
    int t = bt & (T_ - 1);
    int wave = threadIdx.x >> 6;
    int lane = threadIdx.x & 63;
    int l15 = lane & 15;
    int lk = lane >> 4;
    int n0 = wave * 64;

    f32x4 acc[MT][4];
    #pragma unroll
    for (int i = 0; i < MT; ++i)
        #pragma unroll
        for (int j = 0; j < 4; ++j)
            acc[i][j] = (f32x4){0.f, 0.f, 0.f, 0.f};

    if (t > 0) {
        const _Float16* A_h = Ah + (size_t)(bt - 1) * M * N_;
        const _Float16* A_l = Al + (size_t)(bt - 1) * M * N_;
        const _Float16* B_h = STh + (size_t)bt * N_ * N_;
        const _Float16* B_l = STl + (size_t)bt * N_ * N_;
        #pragma unroll
        for (int kk = 0; kk < 8; ++kk) {
            int kof = kk * 32 + lk * 8;
            half8 ah[MT], al[MT];
            #pragma unroll
            for (int i = 0; i < MT; ++i) {
                ah[i] = *(const half8*)(A_h + (size_t)(i * 16 + l15) * N_ + kof);
                al[i] = *(const half8*)(A_l + (size_t)(i * 16 + l15) * N_ + kof);
            }
            #pragma unroll
            for (int j = 0; j < 4; ++j) {
                half8 bh = *(const half8*)(B_h + (size_t)(n0 + j * 16 + l15) * N_ + kof);
                half8 bl = *(const half8*)(B_l + (size_t)(n0 + j * 16 + l15) * N_ + kof);
                #pragma unroll
                for (int i = 0; i < MT; ++i) {
                    acc[i][j] = __builtin_amdgcn_mfma_f32_16x16x32_f16(ah[i], bh, acc[i][j], 0, 0, 0);
                    acc[i][j] = __builtin_amdgcn_mfma_f32_16x16x32_f16(al[i], bh, acc[i][j], 0, 0, 0);
                    acc[i][j] = __builtin_amdgcn_mfma_f32_16x16x32_f16(ah[i], bl, acc[i][j], 0, 0, 0);
                }
            }
        }
    }
    _Float16* O_h = Oh + (size_t)bt * M * N_;
    _Float16* O_l = Ol + (size_t)bt * M * N_;
    #pragma unroll
    for (int i = 0; i < MT; ++i)
        #pragma unroll
        for (int j = 0; j < 4; ++j)
            #pragma unroll
            for (int r = 0; r < 4; ++r) {
                float v = acc[i][j][r];
                _Float16 h = (_Float16)v;
                size_t idx = (size_t)(i * 16 + lk * 4 + r) * N_ + n0 + j * 16 + l15;
                O_h[idx] = h;
                O_l[idx] = (_Float16)(v - (float)h);
            }
}

// ---------------- K2: V1 = U1(t-1)@S(t); y1 = tanh(b1 + W1 ⋅ [x,U1,V1]) ----
__global__ void k_layer1b(const _Float16* __restrict__ U1h, const _Float16* __restrict__ U1l,
                          const _Float16* __restrict__ STh, const _Float16* __restrict__ STl,
                          const float* __restrict__ x,
                          const float* __restrict__ W1,  // (64,3,12)
                          const float* __restrict__ b1,
                          _Float16* __restrict__ Y1h, _Float16* __restrict__ Y1l) {
    __shared__ float v1s[16][260];
    int bt = blockIdx.x;
    int t = bt & (T_ - 1);
    int wave = threadIdx.x >> 6;
    int lane = threadIdx.x & 63;
    int l15 = lane & 15;
    int lk = lane >> 4;
    int n0 = wave * 64;

    f32x4 acc[4];
    #pragma unroll
    for (int j = 0; j < 4; ++j) acc[j] = (f32x4){0.f, 0.f, 0.f, 0.f};

    if (t > 0) {
        const _Float16* A_h = U1h + (size_t)(bt - 1) * 16 * N_;
        const _Float16* A_l = U1l + (size_t)(bt - 1) * 16 * N_;
        const _Float16* B_h = STh + (size_t)bt * N_ * N_;
        const _Float16* B_l = STl + (size_t)bt * N_ * N_;
        #pragma unroll
        for (int kk = 0; kk < 8; ++kk) {
            int kof = kk * 32 + lk * 8;
            half8 ah = *(const half8*)(A_h + (size_t)l15 * N_ + kof);
            half8 al = *(const half8*)(A_l + (size_t)l15 * N_ + kof);
            #pragma unroll
            for (int j = 0; j < 4; ++j) {
                half8 bh = *(const half8*)(B_h + (size_t)(n0 + j * 16 + l15) * N_ + kof);
                half8 bl = *(const half8*)(B_l + (size_t)(n0 + j * 16 + l15) * N_ + kof);
                acc[j] = __builtin_amdgcn_mfma_f32_16x16x32_f16(ah, bh, acc[j], 0, 0, 0);
                acc[j] = __builtin_amdgcn_mfma_f32_16x16x32_f16(al, bh, acc[j], 0, 0, 0);
                acc[j] = __builtin_amdgcn_mfma_f32_16x16x32_f16(ah, bl, acc[j], 0, 0, 0);
            }
        }
    }
    #pragma unroll
    for (int j = 0; j < 4; ++j)
        #pragma unroll
        for (int r = 0; r < 4; ++r)
            v1s[lk * 4 + r][n0 + j * 16 + l15] = acc[j][r];
    __syncthreads();

    // combine: one thread per column n
    int n = threadIdx.x;
    const float* xc = x + (size_t)bt * F0 * N_;
    const _Float16* u1hc = U1h + (size_t)bt * 16 * N_;
    const _Float16* u1lc = U1l + (size_t)bt * 16 * N_;
    float z0[F0], z1[F0], z2[F0];
    #pragma unroll
    for (int g = 0; g < F0; ++g) {
        z0[g] = xc[(size_t)g * N_ + n];
        z1[g] = (float)u1hc[(size_t)g * N_ + n] + (float)u1lc[(size_t)g * N_ + n];
        z2[g] = v1s[g][n];
    }
    _Float16* yh = Y1h + (size_t)bt * F1 * N_;
    _Float16* yl = Y1l + (size_t)bt * F1 * N_;
    #pragma unroll
    for (int f = 0; f < F1; ++f) {
        float a2 = b1[f];
        const float* w = W1 + f * 36;
        #pragma unroll
        for (int g = 0; g < F0; ++g)
            a2 += w[g] * z0[g] + w[12 + g] * z1[g] + w[24 + g] * z2[g];
        float yv = tanh_fast(a2);
        _Float16 h = (_Float16)yv;
        yh[(size_t)f * N_ + n] = h;
        yl[(size_t)f * N_ + n] = (_Float16)(yv - (float)h);
    }
}

// ---------------- K4: V2 = U2(t-1)@S(t); y2 = tanh(b2 + W2 ⋅ [y1,U2,V2]);
//                  readout h = tanh(A1 y2 + c1); out = A2 h + c2 ------------
__global__ void k_layer2b(const _Float16* __restrict__ U2h, const _Float16* __restrict__ U2l,
                          const _Float16* __restrict__ STh, const _Float16* __restrict__ STl,
                          const _Float16* __restrict__ Y1h, const _Float16* __restrict__ Y1l,
                          const float* __restrict__ W2,  // (32,3,64)
                          const float* __restrict__ b2,
                          const float* __restrict__ A1, const float* __restrict__ c1,
                          const float* __restrict__ A2, const float* __restrict__ c2,
                          float* __restrict__ out) {
    __shared__ float v2s[32][260];  // two 32-row phases, 33 KB
    int bt = blockIdx.x;
    int t = bt & (T_ - 1);
    int wave = threadIdx.x >> 6;
    int lane = threadIdx.x & 63;
    int l15 = lane & 15;
    int lk = lane >> 4;
    int n0 = wave * 64;

    f32x4 acc[4][4];
    #pragma unroll
    for (int i = 0; i < 4; ++i)
        #pragma unroll
        for (int j = 0; j < 4; ++j)
            acc[i][j] = (f32x4){0.f, 0.f, 0.f, 0.f};

    if (t > 0) {
        const _Float16* A_h = U2h + (size_t)(bt - 1) * 64 * N_;
        const _Float16* A_l = U2l + (size_t)(bt - 1) * 64 * N_;
        const _Float16* B_h = STh + (size_t)bt * N_ * N_;
        const _Float16* B_l = STl + (size_t)bt * N_ * N_;
        #pragma unroll
        for (int kk = 0; kk < 8; ++kk) {
            int kof = kk * 32 + lk * 8;
            half8 ah[4], al[4];
            #pragma unroll
            for (int i = 0; i < 4; ++i) {
                ah[i] = *(const half8*)(A_h + (size_t)(i * 16 + l15) * N_ + kof);
                al[i] = *(const half8*)(A_l + (size_t)(i * 16 + l15) * N_ + kof);
            }
            #pragma unroll
            for (int j = 0; j < 4; ++j) {
                half8 bh = *(const half8*)(B_h + (size_t)(n0 + j * 16 + l15) * N_ + kof);
                half8 bl = *(const half8*)(B_l + (size_t)(n0 + j * 16 + l15) * N_ + kof);
                #pragma unroll
                for (int i = 0; i < 4; ++i) {
                    acc[i][j] = __builtin_amdgcn_mfma_f32_16x16x32_f16(ah[i], bh, acc[i][j], 0, 0, 0);
                    acc[i][j] = __builtin_amdgcn_mfma_f32_16x16x32_f16(al[i], bh, acc[i][j], 0, 0, 0);
                    acc[i][j] = __builtin_amdgcn_mfma_f32_16x16x32_f16(ah[i], bl, acc[i][j], 0, 0, 0);
                }
            }
        }
    }

    int n = threadIdx.x;
    float y2[F2];
    #pragma unroll
    for (int f = 0; f < F2; ++f) y2[f] = b2[f];

    // y1 and U2 contributions (global, coalesced per row)
    {
        float col[64];
        const _Float16* y1hc = Y1h + (size_t)bt * 64 * N_;
        const _Float16* y1lc = Y1l + (size_t)bt * 64 * N_;
        #pragma unroll
        for (int g = 0; g < 64; ++g)
            col[g] = (float)y1hc[(size_t)g * N_ + n] + (float)y1lc[(size_t)g * N_ + n];
        #pragma unroll
        for (int f = 0; f < F2; ++f) {
            const float* w = W2 + f * 192;
            float s = 0.f;
            #pragma unroll
            for (int g = 0; g < 64; ++g) s += w[g] * col[g];
            y2[f] += s;
        }
        const _Float16* u2hc = U2h + (size_t)bt * 64 * N_;
        const _Float16* u2lc = U2l + (size_t)bt * 64 * N_;
        #pragma unroll
        for (int g = 0; g < 64; ++g)
            col[g] = (float)u2hc[(size_t)g * N_ + n] + (float)u2lc[(size_t)g * N_ + n];
        #pragma unroll
        for (int f = 0; f < F2; ++f) {
            const float* w = W2 + f * 192 + 64;
            float s = 0.f;
            #pragma unroll
            for (int g = 0; g < 64; ++g) s += w[g] * col[g];
            y2[f] += s;
        }
    }

    // V2 contribution in two 32-row phases through LDS
    #pragma unroll
    for (int ph = 0; ph < 2; ++ph) {
        __syncthreads();
        #pragma unroll
        for (int i = 0; i < 2; ++i)
            #pragma unroll
            for (int j = 0; j < 4; ++j)
                #pragma unroll
                for (int r = 0; r < 4; ++r)
                    v2s[i * 16 + lk * 4 + r][n0 + j * 16 + l15] = acc[ph * 2 + i][j][r];
        __syncthreads();
        float col[32];
        #pragma unroll
        for (int g = 0; g < 32; ++g) col[g] = v2s[g][n];
        #pragma unroll
        for (int f = 0; f < F2; ++f) {
            const float* w = W2 + f * 192 + 128 + ph * 32;
            float s = 0.f;
            #pragma unroll
            for (int g = 0; g < 32; ++g) s += w[g] * col[g];
            y2[f] += s;
        }
    }

    #pragma unroll
    for (int f = 0; f < F2; ++f) y2[f] = tanh_fast(y2[f]);

    float h[32];
    #pragma unroll
    for (int j = 0; j < 32; ++j) {
        float s = c1[j];
        const float* a1 = A1 + j * 32;
        #pragma unroll
        for (int f = 0; f < 32; ++f) s += a1[f] * y2[f];
        h[j] = tanh_fast(s);
    }
    #pragma unroll
    for (int r = 0; r < 2; ++r) {
        float s = c2[r];
        const float* a2 = A2 + r * 32;
        #pragma unroll
        for (int j = 0; j < 32; ++j) s += a2[j] * h[j];
        out[((size_t)bt * 2 + r) * N_ + n] = s;
    }
}

extern "C" void kernel_launch(void* const* d_in, const int* in_sizes, int n_in,
                              void* d_out, int out_size, void* d_ws, size_t ws_size,
                              hipStream_t stream) {
    const float* x  = (const float*)d_in[0];
    const float* S  = (const float*)d_in[1];
    const float* W1 = (const float*)d_in[2];
    const float* b1 = (const float*)d_in[3];
    const float* W2 = (const float*)d_in[4];
    const float* b2 = (const float*)d_in[5];
    const float* A1 = (const float*)d_in[6];
    const float* c1 = (const float*)d_in[7];
    const float* A2 = (const float*)d_in[8];
    const float* c2 = (const float*)d_in[9];
    float* out = (float*)d_out;

    // workspace layout (bytes)
    char* ws = (char*)d_ws;
    const size_t SZ_ST = (size_t)BT_ * N_ * N_ * 2;   // 67,108,864 per plane
    const size_t SZ_XH = (size_t)BT_ * 16 * N_ * 2;   //  4,194,304 per plane
    const size_t SZ_Y1 = (size_t)BT_ * 64 * N_ * 2;   // 16,777,216 per plane
    size_t off = 0;
    _Float16* STh = (_Float16*)(ws + off); off += SZ_ST;
    _Float16* STl = (_Float16*)(ws + off); off += SZ_ST;
    _Float16* xh  = (_Float16*)(ws + off); off += SZ_XH;
    _Float16* xl  = (_Float16*)(ws + off); off += SZ_XH;
    _Float16* U1h = (_Float16*)(ws + off); off += SZ_XH;
    _Float16* U1l = (_Float16*)(ws + off); off += SZ_XH;
    _Float16* Y1h = (_Float16*)(ws + off); off += SZ_Y1;
    _Float16* Y1l = (_Float16*)(ws + off); off += SZ_Y1;
    _Float16* U2h = (_Float16*)(ws + off); off += SZ_Y1;
    _Float16* U2l = (_Float16*)(ws + off); off += SZ_Y1;
    if (ws_size < off) return;  // insufficient scratch -> clean failure

    k_transpose_s<<<BT_, 256, 0, stream>>>(S, STh, STl);
    k_convert_x<<<(BT_ * 16 * N_) / 256, 256, 0, stream>>>(x, xh, xl, BT_ * 16 * N_);
    k_chain<1><<<BT_, 256, 0, stream>>>(xh, xl, STh, STl, U1h, U1l);
    k_layer1b<<<BT_, 256, 0, stream>>>(U1h, U1l, STh, STl, x, W1, b1, Y1h, Y1l);
    k_chain<4><<<BT_, 256, 0, stream>>>(Y1h, Y1l, STh, STl, U2h, U2l);
    k_layer2b<<<BT_, 256, 0, stream>>>(U2h, U2l, STh, STl, Y1h, Y1l, W2, b2, A1, c1, A2, c2, out);
}

// Round 3
// 431.829 us; speedup vs baseline: 1.4485x; 1.4485x over previous
//
#include <hip/hip_runtime.h>
#include <hip/hip_fp16.h>

typedef _Float16 half8 __attribute__((ext_vector_type(8)));
typedef _Float16 half4v __attribute__((ext_vector_type(4)));
typedef float f32x4 __attribute__((ext_vector_type(4)));

static constexpr int B_ = 8, T_ = 64, N_ = 256;
static constexpr int F0 = 12, F1 = 64, F2 = 32;
static constexpr int BT_ = B_ * T_;

__device__ inline float tanh_fast(float x) {
    x = fminf(20.f, fmaxf(-20.f, x));
    float e = __expf(2.f * x);
    return (e - 1.f) / (e + 1.f);
}

// ---------------- K0: S (BT,256,256) f32 -> S^T hi/lo fp16 planes ----------
// STh/STl[bt][n][m] = split(S[bt][m][n]); contraction index m is contiguous.
// grid (BT_, 4): block handles output rows n0..n0+63 (i.e. input cols), all m.
__global__ void k_transpose_s(const float* __restrict__ S,
                              _Float16* __restrict__ STh, _Float16* __restrict__ STl) {
    int bt = blockIdx.x;
    int n0 = blockIdx.y * 64;
    const float* s = S + (size_t)bt * N_ * N_;
    _Float16* sth = STh + (size_t)bt * N_ * N_;
    _Float16* stl = STl + (size_t)bt * N_ * N_;
    __shared__ float tile[64][65];
    int tx = threadIdx.x & 15;   // float4 group within 64 cols
    int ty = threadIdx.x >> 4;   // 0..31
    for (int tm = 0; tm < N_; tm += 64) {
        #pragma unroll
        for (int r = ty; r < 64; r += 32) {
            float4 v = *(const float4*)(s + (size_t)(tm + r) * N_ + n0 + tx * 4);
            tile[r][tx * 4 + 0] = v.x;
            tile[r][tx * 4 + 1] = v.y;
            tile[r][tx * 4 + 2] = v.z;
            tile[r][tx * 4 + 3] = v.w;
        }
        __syncthreads();
        #pragma unroll
        for (int rr = ty; rr < 64; rr += 32) {
            half4v h, l;
            #pragma unroll
            for (int c = 0; c < 4; ++c) {
                float v = tile[tx * 4 + c][rr];
                _Float16 hh = (_Float16)v;
                h[c] = hh;
                l[c] = (_Float16)(v - (float)hh);
            }
            size_t o = (size_t)(n0 + rr) * N_ + tm + tx * 4;
            *(half4v*)(sth + o) = h;
            *(half4v*)(stl + o) = l;
        }
        __syncthreads();
    }
}

// ---------------- K1: U1(b,t) = x(b,t-1) @ S(b,t), x read as f32, split in-reg
__global__ void k_chain1x(const float* __restrict__ x,
                          const _Float16* __restrict__ STh, const _Float16* __restrict__ STl,
                          _Float16* __restrict__ Oh, _Float16* __restrict__ Ol) {
    int bt = blockIdx.x;
    int t = bt & (T_ - 1);
    int wave = threadIdx.x >> 6;
    int lane = threadIdx.x & 63;
    int l15 = lane & 15;
    int lk = lane >> 4;
    int n0 = wave * 64;

    f32x4 acc[4];
    #pragma unroll
    for (int j = 0; j < 4; ++j) acc[j] = (f32x4){0.f, 0.f, 0.f, 0.f};

    if (t > 0) {
        const float* A = x + (size_t)(bt - 1) * F0 * N_;
        const _Float16* B_h = STh + (size_t)bt * N_ * N_;
        const _Float16* B_l = STl + (size_t)bt * N_ * N_;
        #pragma unroll
        for (int kk = 0; kk < 8; ++kk) {
            int kof = kk * 32 + lk * 8;
            half8 ah = {}, al = {};
            if (l15 < F0) {
                const float* ar = A + (size_t)l15 * N_ + kof;
                float4 v0 = *(const float4*)(ar);
                float4 v1 = *(const float4*)(ar + 4);
                float vv[8] = {v0.x, v0.y, v0.z, v0.w, v1.x, v1.y, v1.z, v1.w};
                #pragma unroll
                for (int c = 0; c < 8; ++c) {
                    _Float16 hh = (_Float16)vv[c];
                    ah[c] = hh;
                    al[c] = (_Float16)(vv[c] - (float)hh);
                }
            }
            #pragma unroll
            for (int j = 0; j < 4; ++j) {
                half8 bh = *(const half8*)(B_h + (size_t)(n0 + j * 16 + l15) * N_ + kof);
                half8 bl = *(const half8*)(B_l + (size_t)(n0 + j * 16 + l15) * N_ + kof);
                acc[j] = __builtin_amdgcn_mfma_f32_16x16x32_f16(ah, bh, acc[j], 0, 0, 0);
                acc[j] = __builtin_amdgcn_mfma_f32_16x16x32_f16(al, bh, acc[j], 0, 0, 0);
                acc[j] = __builtin_amdgcn_mfma_f32_16x16x32_f16(ah, bl, acc[j], 0, 0, 0);
            }
        }
    }
    _Float16* O_h = Oh + (size_t)bt * 16 * N_;
    _Float16* O_l = Ol + (size_t)bt * 16 * N_;
    #pragma unroll
    for (int j = 0; j < 4; ++j)
        #pragma unroll
        for (int r = 0; r < 4; ++r) {
            float v = acc[j][r];
            _Float16 h = (_Float16)v;
            size_t idx = (size_t)(lk * 4 + r) * N_ + n0 + j * 16 + l15;
            O_h[idx] = h;
            O_l[idx] = (_Float16)(v - (float)h);
        }
}

// ---------------- chain matmul: Out(b,t) = Aprev(b,t-1) @ S(b,t), split-fp16 --
template <int MT>
__global__ void k_chain(const _Float16* __restrict__ Ah, const _Float16* __restrict__ Al,
                        const _Float16* __restrict__ STh, const _Float16* __restrict__ STl,
                        _Float16* __restrict__ Oh, _Float16* __restrict__ Ol) {
    constexpr int M = 16 * MT;
    int bt = blockIdx.x;
    int t = bt & (T_ - 1);
    int wave = threadIdx.x >> 6;
    int lane = threadIdx.x & 63;
    int l15 = lane & 15;
    int lk = lane >> 4;
    int n0 = wave * 64;

    f32x4 acc[MT][4];
    #pragma unroll
    for (int i = 0; i < MT; ++i)
        #pragma unroll
        for (int j = 0; j < 4; ++j)
            acc[i][j] = (f32x4){0.f, 0.f, 0.f, 0.f};

    if (t > 0) {
        const _Float16* A_h = Ah + (size_t)(bt - 1) * M * N_;
        const _Float16* A_l = Al + (size_t)(bt - 1) * M * N_;
        const _Float16* B_h = STh + (size_t)bt * N_ * N_;
        const _Float16* B_l = STl + (size_t)bt * N_ * N_;
        #pragma unroll
        for (int kk = 0; kk < 8; ++kk) {
            int kof = kk * 32 + lk * 8;
            half8 ah[MT], al[MT];
            #pragma unroll
            for (int i = 0; i < MT; ++i) {
                ah[i] = *(const half8*)(A_h + (size_t)(i * 16 + l15) * N_ + kof);
                al[i] = *(const half8*)(A_l + (size_t)(i * 16 + l15) * N_ + kof);
            }
            #pragma unroll
            for (int j = 0; j < 4; ++j) {
                half8 bh = *(const half8*)(B_h + (size_t)(n0 + j * 16 + l15) * N_ + kof);
                half8 bl = *(const half8*)(B_l + (size_t)(n0 + j * 16 + l15) * N_ + kof);
                #pragma unroll
                for (int i = 0; i < MT; ++i) {
                    acc[i][j] = __builtin_amdgcn_mfma_f32_16x16x32_f16(ah[i], bh, acc[i][j], 0, 0, 0);
                    acc[i][j] = __builtin_amdgcn_mfma_f32_16x16x32_f16(al[i], bh, acc[i][j], 0, 0, 0);
                    acc[i][j] = __builtin_amdgcn_mfma_f32_16x16x32_f16(ah[i], bl, acc[i][j], 0, 0, 0);
                }
            }
        }
    }
    _Float16* O_h = Oh + (size_t)bt * M * N_;
    _Float16* O_l = Ol + (size_t)bt * M * N_;
    #pragma unroll
    for (int i = 0; i < MT; ++i)
        #pragma unroll
        for (int j = 0; j < 4; ++j)
            #pragma unroll
            for (int r = 0; r < 4; ++r) {
                float v = acc[i][j][r];
                _Float16 h = (_Float16)v;
                size_t idx = (size_t)(i * 16 + lk * 4 + r) * N_ + n0 + j * 16 + l15;
                O_h[idx] = h;
                O_l[idx] = (_Float16)(v - (float)h);
            }
}

// ---------------- K2: V1 = U1(t-1)@S(t); y1 = tanh(b1 + W1 ⋅ [x,U1,V1]) ----
__global__ void k_layer1b(const _Float16* __restrict__ U1h, const _Float16* __restrict__ U1l,
                          const _Float16* __restrict__ STh, const _Float16* __restrict__ STl,
                          const float* __restrict__ x,
                          const float* __restrict__ W1,  // (64,3,12)
                          const float* __restrict__ b1,
                          _Float16* __restrict__ Y1h, _Float16* __restrict__ Y1l) {
    __shared__ float v1s[16][260];
    int bt = blockIdx.x;
    int t = bt & (T_ - 1);
    int wave = threadIdx.x >> 6;
    int lane = threadIdx.x & 63;
    int l15 = lane & 15;
    int lk = lane >> 4;
    int n0 = wave * 64;

    f32x4 acc[4];
    #pragma unroll
    for (int j = 0; j < 4; ++j) acc[j] = (f32x4){0.f, 0.f, 0.f, 0.f};

    if (t > 0) {
        const _Float16* A_h = U1h + (size_t)(bt - 1) * 16 * N_;
        const _Float16* A_l = U1l + (size_t)(bt - 1) * 16 * N_;
        const _Float16* B_h = STh + (size_t)bt * N_ * N_;
        const _Float16* B_l = STl + (size_t)bt * N_ * N_;
        #pragma unroll
        for (int kk = 0; kk < 8; ++kk) {
            int kof = kk * 32 + lk * 8;
            half8 ah = *(const half8*)(A_h + (size_t)l15 * N_ + kof);
            half8 al = *(const half8*)(A_l + (size_t)l15 * N_ + kof);
            #pragma unroll
            for (int j = 0; j < 4; ++j) {
                half8 bh = *(const half8*)(B_h + (size_t)(n0 + j * 16 + l15) * N_ + kof);
                half8 bl = *(const half8*)(B_l + (size_t)(n0 + j * 16 + l15) * N_ + kof);
                acc[j] = __builtin_amdgcn_mfma_f32_16x16x32_f16(ah, bh, acc[j], 0, 0, 0);
                acc[j] = __builtin_amdgcn_mfma_f32_16x16x32_f16(al, bh, acc[j], 0, 0, 0);
                acc[j] = __builtin_amdgcn_mfma_f32_16x16x32_f16(ah, bl, acc[j], 0, 0, 0);
            }
        }
    }
    #pragma unroll
    for (int j = 0; j < 4; ++j)
        #pragma unroll
        for (int r = 0; r < 4; ++r)
            v1s[lk * 4 + r][n0 + j * 16 + l15] = acc[j][r];
    __syncthreads();

    // combine: one thread per column n
    int n = threadIdx.x;
    const float* xc = x + (size_t)bt * F0 * N_;
    const _Float16* u1hc = U1h + (size_t)bt * 16 * N_;
    const _Float16* u1lc = U1l + (size_t)bt * 16 * N_;
    float z0[F0], z1[F0], z2[F0];
    #pragma unroll
    for (int g = 0; g < F0; ++g) {
        z0[g] = xc[(size_t)g * N_ + n];
        z1[g] = (float)u1hc[(size_t)g * N_ + n] + (float)u1lc[(size_t)g * N_ + n];
        z2[g] = v1s[g][n];
    }
    _Float16* yh = Y1h + (size_t)bt * F1 * N_;
    _Float16* yl = Y1l + (size_t)bt * F1 * N_;
    #pragma unroll
    for (int f = 0; f < F1; ++f) {
        float a2 = b1[f];
        const float* w = W1 + f * 36;
        #pragma unroll
        for (int g = 0; g < F0; ++g)
            a2 += w[g] * z0[g] + w[12 + g] * z1[g] + w[24 + g] * z2[g];
        float yv = tanh_fast(a2);
        _Float16 h = (_Float16)yv;
        yh[(size_t)f * N_ + n] = h;
        yl[(size_t)f * N_ + n] = (_Float16)(yv - (float)h);
    }
}

// ---------------- K4: V2 = U2(t-1)@S(t); y2 = tanh(b2 + W2 ⋅ [y1,U2,V2]);
//                  readout h = tanh(A1 y2 + c1); out = A2 h + c2 ------------
__global__ void k_layer2b(const _Float16* __restrict__ U2h, const _Float16* __restrict__ U2l,
                          const _Float16* __restrict__ STh, const _Float16* __restrict__ STl,
                          const _Float16* __restrict__ Y1h, const _Float16* __restrict__ Y1l,
                          const float* __restrict__ W2,  // (32,3,64)
                          const float* __restrict__ b2,
                          const float* __restrict__ A1, const float* __restrict__ c1,
                          const float* __restrict__ A2, const float* __restrict__ c2,
                          float* __restrict__ out) {
    __shared__ float v2s[32][260];  // two 32-row phases, 33 KB
    int bt = blockIdx.x;
    int t = bt & (T_ - 1);
    int wave = threadIdx.x >> 6;
    int lane = threadIdx.x & 63;
    int l15 = lane & 15;
    int lk = lane >> 4;
    int n0 = wave * 64;

    f32x4 acc[4][4];
    #pragma unroll
    for (int i = 0; i < 4; ++i)
        #pragma unroll
        for (int j = 0; j < 4; ++j)
            acc[i][j] = (f32x4){0.f, 0.f, 0.f, 0.f};

    if (t > 0) {
        const _Float16* A_h = U2h + (size_t)(bt - 1) * 64 * N_;
        const _Float16* A_l = U2l + (size_t)(bt - 1) * 64 * N_;
        const _Float16* B_h = STh + (size_t)bt * N_ * N_;
        const _Float16* B_l = STl + (size_t)bt * N_ * N_;
        #pragma unroll
        for (int kk = 0; kk < 8; ++kk) {
            int kof = kk * 32 + lk * 8;
            half8 ah[4], al[4];
            #pragma unroll
            for (int i = 0; i < 4; ++i) {
                ah[i] = *(const half8*)(A_h + (size_t)(i * 16 + l15) * N_ + kof);
                al[i] = *(const half8*)(A_l + (size_t)(i * 16 + l15) * N_ + kof);
            }
            #pragma unroll
            for (int j = 0; j < 4; ++j) {
                half8 bh = *(const half8*)(B_h + (size_t)(n0 + j * 16 + l15) * N_ + kof);
                half8 bl = *(const half8*)(B_l + (size_t)(n0 + j * 16 + l15) * N_ + kof);
                #pragma unroll
                for (int i = 0; i < 4; ++i) {
                    acc[i][j] = __builtin_amdgcn_mfma_f32_16x16x32_f16(ah[i], bh, acc[i][j], 0, 0, 0);
                    acc[i][j] = __builtin_amdgcn_mfma_f32_16x16x32_f16(al[i], bh, acc[i][j], 0, 0, 0);
                    acc[i][j] = __builtin_amdgcn_mfma_f32_16x16x32_f16(ah[i], bl, acc[i][j], 0, 0, 0);
                }
            }
        }
    }

    int n = threadIdx.x;
    float y2[F2];
    #pragma unroll
    for (int f = 0; f < F2; ++f) y2[f] = b2[f];

    // y1 and U2 contributions (global, coalesced per row)
    {
        float col[64];
        const _Float16* y1hc = Y1h + (size_t)bt * 64 * N_;
        const _Float16* y1lc = Y1l + (size_t)bt * 64 * N_;
        #pragma unroll
        for (int g = 0; g < 64; ++g)
            col[g] = (float)y1hc[(size_t)g * N_ + n] + (float)y1lc[(size_t)g * N_ + n];
        #pragma unroll
        for (int f = 0; f < F2; ++f) {
            const float* w = W2 + f * 192;
            float s = 0.f;
            #pragma unroll
            for (int g = 0; g < 64; ++g) s += w[g] * col[g];
            y2[f] += s;
        }
        const _Float16* u2hc = U2h + (size_t)bt * 64 * N_;
        const _Float16* u2lc = U2l + (size_t)bt * 64 * N_;
        #pragma unroll
        for (int g = 0; g < 64; ++g)
            col[g] = (float)u2hc[(size_t)g * N_ + n] + (float)u2lc[(size_t)g * N_ + n];
        #pragma unroll
        for (int f = 0; f < F2; ++f) {
            const float* w = W2 + f * 192 + 64;
            float s = 0.f;
            #pragma unroll
            for (int g = 0; g < 64; ++g) s += w[g] * col[g];
            y2[f] += s;
        }
    }

    // V2 contribution in two 32-row phases through LDS
    #pragma unroll
    for (int ph = 0; ph < 2; ++ph) {
        __syncthreads();
        #pragma unroll
        for (int i = 0; i < 2; ++i)
            #pragma unroll
            for (int j = 0; j < 4; ++j)
                #pragma unroll
                for (int r = 0; r < 4; ++r)
                    v2s[i * 16 + lk * 4 + r][n0 + j * 16 + l15] = acc[ph * 2 + i][j][r];
        __syncthreads();
        float col[32];
        #pragma unroll
        for (int g = 0; g < 32; ++g) col[g] = v2s[g][n];
        #pragma unroll
        for (int f = 0; f < F2; ++f) {
            const float* w = W2 + f * 192 + 128 + ph * 32;
            float s = 0.f;
            #pragma unroll
            for (int g = 0; g < 32; ++g) s += w[g] * col[g];
            y2[f] += s;
        }
    }

    #pragma unroll
    for (int f = 0; f < F2; ++f) y2[f] = tanh_fast(y2[f]);

    float h[32];
    #pragma unroll
    for (int j = 0; j < 32; ++j) {
        float s = c1[j];
        const float* a1 = A1 + j * 32;
        #pragma unroll
        for (int f = 0; f < 32; ++f) s += a1[f] * y2[f];
        h[j] = tanh_fast(s);
    }
    #pragma unroll
    for (int r = 0; r < 2; ++r) {
        float s = c2[r];
        const float* a2 = A2 + r * 32;
        #pragma unroll
        for (int j = 0; j < 32; ++j) s += a2[j] * h[j];
        out[((size_t)bt * 2 + r) * N_ + n] = s;
    }
}

extern "C" void kernel_launch(void* const* d_in, const int* in_sizes, int n_in,
                              void* d_out, int out_size, void* d_ws, size_t ws_size,
                              hipStream_t stream) {
    const float* x  = (const float*)d_in[0];
    const float* S  = (const float*)d_in[1];
    const float* W1 = (const float*)d_in[2];
    const float* b1 = (const float*)d_in[3];
    const float* W2 = (const float*)d_in[4];
    const float* b2 = (const float*)d_in[5];
    const float* A1 = (const float*)d_in[6];
    const float* c1 = (const float*)d_in[7];
    const float* A2 = (const float*)d_in[8];
    const float* c2 = (const float*)d_in[9];
    float* out = (float*)d_out;

    // workspace layout (bytes)
    char* ws = (char*)d_ws;
    const size_t SZ_ST = (size_t)BT_ * N_ * N_ * 2;   // 67,108,864 per plane
    const size_t SZ_U1 = (size_t)BT_ * 16 * N_ * 2;   //  4,194,304 per plane
    const size_t SZ_Y1 = (size_t)BT_ * 64 * N_ * 2;   // 16,777,216 per plane
    size_t off = 0;
    _Float16* STh = (_Float16*)(ws + off); off += SZ_ST;
    _Float16* STl = (_Float16*)(ws + off); off += SZ_ST;
    _Float16* U1h = (_Float16*)(ws + off); off += SZ_U1;
    _Float16* U1l = (_Float16*)(ws + off); off += SZ_U1;
    _Float16* Y1h = (_Float16*)(ws + off); off += SZ_Y1;
    _Float16* Y1l = (_Float16*)(ws + off); off += SZ_Y1;
    _Float16* U2h = (_Float16*)(ws + off); off += SZ_Y1;
    _Float16* U2l = (_Float16*)(ws + off); off += SZ_Y1;
    if (ws_size < off) return;  // insufficient scratch -> clean failure

    k_transpose_s<<<dim3(BT_, 4), 512, 0, stream>>>(S, STh, STl);
    k_chain1x<<<BT_, 256, 0, stream>>>(x, STh, STl, U1h, U1l);
    k_layer1b<<<BT_, 256, 0, stream>>>(U1h, U1l, STh, STl, x, W1, b1, Y1h, Y1l);
    k_chain<4><<<BT_, 256, 0, stream>>>(Y1h, Y1l, STh, STl, U2h, U2l);
    k_layer2b<<<BT_, 256, 0, stream>>>(U2h, U2l, STh, STl, Y1h, Y1l, W2, b2, A1, c1, A2, c2, out);
}

// Round 4
// 379.904 us; speedup vs baseline: 1.6465x; 1.1367x over previous
//
#include <hip/hip_runtime.h>
#include <hip/hip_fp16.h>

typedef _Float16 half8 __attribute__((ext_vector_type(8)));
typedef _Float16 half4v __attribute__((ext_vector_type(4)));
typedef float f32x4 __attribute__((ext_vector_type(4)));

static constexpr int B_ = 8, T_ = 64, N_ = 256;
static constexpr int F0 = 12, F1 = 64, F2 = 32;
static constexpr int BT_ = B_ * T_;

__device__ inline float tanh_fast(float x) {
    x = fminf(20.f, fmaxf(-20.f, x));
    float e = __expf(2.f * x);
    return (e - 1.f) / (e + 1.f);
}

// ---------------- K0: S (BT,256,256) f32 -> S^T hi/lo fp16 planes ----------
__global__ void k_transpose_s(const float* __restrict__ S,
                              _Float16* __restrict__ STh, _Float16* __restrict__ STl) {
    int bt = blockIdx.x;
    int n0 = blockIdx.y * 64;
    const float* s = S + (size_t)bt * N_ * N_;
    _Float16* sth = STh + (size_t)bt * N_ * N_;
    _Float16* stl = STl + (size_t)bt * N_ * N_;
    __shared__ float tile[64][65];
    int tx = threadIdx.x & 15;
    int ty = threadIdx.x >> 4;
    for (int tm = 0; tm < N_; tm += 64) {
        #pragma unroll
        for (int r = ty; r < 64; r += 32) {
            float4 v = *(const float4*)(s + (size_t)(tm + r) * N_ + n0 + tx * 4);
            tile[r][tx * 4 + 0] = v.x;
            tile[r][tx * 4 + 1] = v.y;
            tile[r][tx * 4 + 2] = v.z;
            tile[r][tx * 4 + 3] = v.w;
        }
        __syncthreads();
        #pragma unroll
        for (int rr = ty; rr < 64; rr += 32) {
            half4v h, l;
            #pragma unroll
            for (int c = 0; c < 4; ++c) {
                float v = tile[tx * 4 + c][rr];
                _Float16 hh = (_Float16)v;
                h[c] = hh;
                l[c] = (_Float16)(v - (float)hh);
            }
            size_t o = (size_t)(n0 + rr) * N_ + tm + tx * 4;
            *(half4v*)(sth + o) = h;
            *(half4v*)(stl + o) = l;
        }
        __syncthreads();
    }
}

// ---------------- K1: U1(b,t) = x(b,t-1) @ S(b,t), x read as f32, split in-reg
__global__ void k_chain1x(const float* __restrict__ x,
                          const _Float16* __restrict__ STh, const _Float16* __restrict__ STl,
                          _Float16* __restrict__ Oh, _Float16* __restrict__ Ol) {
    int bt = blockIdx.x;
    int t = bt & (T_ - 1);
    int wave = threadIdx.x >> 6;
    int lane = threadIdx.x & 63;
    int l15 = lane & 15;
    int lk = lane >> 4;
    int n0 = wave * 64;

    f32x4 acc[4];
    #pragma unroll
    for (int j = 0; j < 4; ++j) acc[j] = (f32x4){0.f, 0.f, 0.f, 0.f};

    if (t > 0) {
        const float* A = x + (size_t)(bt - 1) * F0 * N_;
        const _Float16* B_h = STh + (size_t)bt * N_ * N_;
        const _Float16* B_l = STl + (size_t)bt * N_ * N_;
        #pragma unroll
        for (int kk = 0; kk < 8; ++kk) {
            int kof = kk * 32 + lk * 8;
            half8 ah = {}, al = {};
            if (l15 < F0) {
                const float* ar = A + (size_t)l15 * N_ + kof;
                float4 v0 = *(const float4*)(ar);
                float4 v1 = *(const float4*)(ar + 4);
                float vv[8] = {v0.x, v0.y, v0.z, v0.w, v1.x, v1.y, v1.z, v1.w};
                #pragma unroll
                for (int c = 0; c < 8; ++c) {
                    _Float16 hh = (_Float16)vv[c];
                    ah[c] = hh;
                    al[c] = (_Float16)(vv[c] - (float)hh);
                }
            }
            #pragma unroll
            for (int j = 0; j < 4; ++j) {
                half8 bh = *(const half8*)(B_h + (size_t)(n0 + j * 16 + l15) * N_ + kof);
                half8 bl = *(const half8*)(B_l + (size_t)(n0 + j * 16 + l15) * N_ + kof);
                acc[j] = __builtin_amdgcn_mfma_f32_16x16x32_f16(ah, bh, acc[j], 0, 0, 0);
                acc[j] = __builtin_amdgcn_mfma_f32_16x16x32_f16(al, bh, acc[j], 0, 0, 0);
                acc[j] = __builtin_amdgcn_mfma_f32_16x16x32_f16(ah, bl, acc[j], 0, 0, 0);
            }
        }
    }
    _Float16* O_h = Oh + (size_t)bt * 16 * N_;
    _Float16* O_l = Ol + (size_t)bt * 16 * N_;
    #pragma unroll
    for (int j = 0; j < 4; ++j)
        #pragma unroll
        for (int r = 0; r < 4; ++r) {
            float v = acc[j][r];
            _Float16 h = (_Float16)v;
            size_t idx = (size_t)(lk * 4 + r) * N_ + n0 + j * 16 + l15;
            O_h[idx] = h;
            O_l[idx] = (_Float16)(v - (float)h);
        }
}

// ---------------- K2: V1 = U1(t-1)@S(t); y1 = tanh(b1 + W1 ⋅ [x,U1,V1]) ----
__global__ void k_layer1b(const _Float16* __restrict__ U1h, const _Float16* __restrict__ U1l,
                          const _Float16* __restrict__ STh, const _Float16* __restrict__ STl,
                          const float* __restrict__ x,
                          const float* __restrict__ W1,  // (64,3,12)
                          const float* __restrict__ b1,
                          _Float16* __restrict__ Y1h, _Float16* __restrict__ Y1l) {
    __shared__ float v1s[16][260];
    int bt = blockIdx.x;
    int t = bt & (T_ - 1);
    int wave = threadIdx.x >> 6;
    int lane = threadIdx.x & 63;
    int l15 = lane & 15;
    int lk = lane >> 4;
    int n0 = wave * 64;

    f32x4 acc[4];
    #pragma unroll
    for (int j = 0; j < 4; ++j) acc[j] = (f32x4){0.f, 0.f, 0.f, 0.f};

    if (t > 0) {
        const _Float16* A_h = U1h + (size_t)(bt - 1) * 16 * N_;
        const _Float16* A_l = U1l + (size_t)(bt - 1) * 16 * N_;
        const _Float16* B_h = STh + (size_t)bt * N_ * N_;
        const _Float16* B_l = STl + (size_t)bt * N_ * N_;
        #pragma unroll
        for (int kk = 0; kk < 8; ++kk) {
            int kof = kk * 32 + lk * 8;
            half8 ah = *(const half8*)(A_h + (size_t)l15 * N_ + kof);
            half8 al = *(const half8*)(A_l + (size_t)l15 * N_ + kof);
            #pragma unroll
            for (int j = 0; j < 4; ++j) {
                half8 bh = *(const half8*)(B_h + (size_t)(n0 + j * 16 + l15) * N_ + kof);
                half8 bl = *(const half8*)(B_l + (size_t)(n0 + j * 16 + l15) * N_ + kof);
                acc[j] = __builtin_amdgcn_mfma_f32_16x16x32_f16(ah, bh, acc[j], 0, 0, 0);
                acc[j] = __builtin_amdgcn_mfma_f32_16x16x32_f16(al, bh, acc[j], 0, 0, 0);
                acc[j] = __builtin_amdgcn_mfma_f32_16x16x32_f16(ah, bl, acc[j], 0, 0, 0);
            }
        }
    }
    #pragma unroll
    for (int j = 0; j < 4; ++j)
        #pragma unroll
        for (int r = 0; r < 4; ++r)
            v1s[lk * 4 + r][n0 + j * 16 + l15] = acc[j][r];
    __syncthreads();

    int n = threadIdx.x;
    const float* xc = x + (size_t)bt * F0 * N_;
    const _Float16* u1hc = U1h + (size_t)bt * 16 * N_;
    const _Float16* u1lc = U1l + (size_t)bt * 16 * N_;
    float z0[F0], z1[F0], z2[F0];
    #pragma unroll
    for (int g = 0; g < F0; ++g) {
        z0[g] = xc[(size_t)g * N_ + n];
        z1[g] = (float)u1hc[(size_t)g * N_ + n] + (float)u1lc[(size_t)g * N_ + n];
        z2[g] = v1s[g][n];
    }
    _Float16* yh = Y1h + (size_t)bt * F1 * N_;
    _Float16* yl = Y1l + (size_t)bt * F1 * N_;
    #pragma unroll
    for (int f = 0; f < F1; ++f) {
        float a2 = b1[f];
        const float* w = W1 + f * 36;
        #pragma unroll
        for (int g = 0; g < F0; ++g)
            a2 += w[g] * z0[g] + w[12 + g] * z1[g] + w[24 + g] * z2[g];
        float yv = tanh_fast(a2);
        _Float16 h = (_Float16)yv;
        yh[(size_t)f * N_ + n] = h;
        yl[(size_t)f * N_ + n] = (_Float16)(yv - (float)h);
    }
}

// ---------------- K3 (fused layer 2 + readout) ------------------------------
// Per (b,t): T = Y1(t-2)@S(t-1)  -> LDS (hi/lo fp16, XOR-swizzled)
//            V2 = T@S(t); U2 = Y1(t-1)@S(t)   (B-fragments shared)
//            y2 = tanh(b2 + W2.[Y1(t), U2, V2]); h = tanh(A1 y2 + c1);
//            out = A2 h + c2
// 8 waves x 32 cols; combine is per-wave (2 lanes per col, f-halves, shfl join).
__global__ __launch_bounds__(512, 4) void k_layer2f(
    const _Float16* __restrict__ Y1h, const _Float16* __restrict__ Y1l,
    const _Float16* __restrict__ STh, const _Float16* __restrict__ STl,
    const float* __restrict__ W2, const float* __restrict__ b2,
    const float* __restrict__ A1, const float* __restrict__ c1,
    const float* __restrict__ A2, const float* __restrict__ c2,
    float* __restrict__ out) {
    __shared__ __align__(16) unsigned char lds_raw[65536];
    _Float16* Th = reinterpret_cast<_Float16*>(lds_raw);         // [64][256] swizzled
    _Float16* Tl = Th + 64 * 256;

    int bid = blockIdx.x;
    int bt = (bid & 7) * 64 + (bid >> 3);   // XCD swizzle: batch b on XCD b
    int t = bt & (T_ - 1);
    int w = threadIdx.x >> 6;
    int lane = threadIdx.x & 63;
    int l15 = lane & 15;
    int lk = lane >> 4;
    int n0 = w * 32;

    // ---- phase 1: T = Y1(t-2) @ S(t-1), cols n0..n0+31 ----
    f32x4 accT[4][2];
    #pragma unroll
    for (int i = 0; i < 4; ++i)
        #pragma unroll
        for (int j = 0; j < 2; ++j) accT[i][j] = (f32x4){0.f, 0.f, 0.f, 0.f};

    if (t >= 2) {
        const _Float16* A_h = Y1h + (size_t)(bt - 2) * 64 * N_;
        const _Float16* A_l = Y1l + (size_t)(bt - 2) * 64 * N_;
        const _Float16* B_h = STh + (size_t)(bt - 1) * N_ * N_;
        const _Float16* B_l = STl + (size_t)(bt - 1) * N_ * N_;
        #pragma unroll
        for (int kk = 0; kk < 8; ++kk) {
            int kof = kk * 32 + lk * 8;
            half8 bh[2], bl[2];
            #pragma unroll
            for (int j = 0; j < 2; ++j) {
                bh[j] = *(const half8*)(B_h + (size_t)(n0 + j * 16 + l15) * N_ + kof);
                bl[j] = *(const half8*)(B_l + (size_t)(n0 + j * 16 + l15) * N_ + kof);
            }
            #pragma unroll
            for (int i = 0; i < 4; ++i) {
                half8 ah = *(const half8*)(A_h + (size_t)(i * 16 + l15) * N_ + kof);
                half8 al = *(const half8*)(A_l + (size_t)(i * 16 + l15) * N_ + kof);
                #pragma unroll
                for (int j = 0; j < 2; ++j) {
                    accT[i][j] = __builtin_amdgcn_mfma_f32_16x16x32_f16(ah, bh[j], accT[i][j], 0, 0, 0);
                    accT[i][j] = __builtin_amdgcn_mfma_f32_16x16x32_f16(al, bh[j], accT[i][j], 0, 0, 0);
                    accT[i][j] = __builtin_amdgcn_mfma_f32_16x16x32_f16(ah, bl[j], accT[i][j], 0, 0, 0);
                }
            }
        }
    }
    // write T (always; zeros when t<2). element-index XOR swizzle = byte ^ ((row&7)<<4)
    #pragma unroll
    for (int i = 0; i < 4; ++i)
        #pragma unroll
        for (int j = 0; j < 2; ++j)
            #pragma unroll
            for (int r = 0; r < 4; ++r) {
                int row = i * 16 + lk * 4 + r;
                int m = n0 + j * 16 + l15;
                float v = accT[i][j][r];
                _Float16 hh = (_Float16)v;
                int eidx = (row * 256 + m) ^ ((row & 7) << 3);
                Th[eidx] = hh;
                Tl[eidx] = (_Float16)(v - (float)hh);
            }
    __syncthreads();

    // ---- phase 2: V2 = T@S(t), U2 = Y1(t-1)@S(t) ----
    f32x4 accV[4][2], accU[4][2];
    #pragma unroll
    for (int i = 0; i < 4; ++i)
        #pragma unroll
        for (int j = 0; j < 2; ++j) {
            accV[i][j] = (f32x4){0.f, 0.f, 0.f, 0.f};
            accU[i][j] = (f32x4){0.f, 0.f, 0.f, 0.f};
        }
    {
        const bool hasU = (t >= 1);
        const _Float16* U_h = Y1h + (size_t)(bt - 1) * 64 * N_;
        const _Float16* U_l = Y1l + (size_t)(bt - 1) * 64 * N_;
        const _Float16* B_h = STh + (size_t)bt * N_ * N_;
        const _Float16* B_l = STl + (size_t)bt * N_ * N_;
        #pragma unroll
        for (int kk = 0; kk < 8; ++kk) {
            int kof = kk * 32 + lk * 8;
            half8 bh[2], bl[2];
            #pragma unroll
            for (int j = 0; j < 2; ++j) {
                bh[j] = *(const half8*)(B_h + (size_t)(n0 + j * 16 + l15) * N_ + kof);
                bl[j] = *(const half8*)(B_l + (size_t)(n0 + j * 16 + l15) * N_ + kof);
            }
            #pragma unroll
            for (int i = 0; i < 4; ++i) {
                int row = i * 16 + l15;
                int e = (row * 256 + kof) ^ ((row & 7) << 3);
                half8 tah = *(const half8*)(Th + e);
                half8 tal = *(const half8*)(Tl + e);
                half8 uah = {}, ual = {};
                if (hasU) {
                    uah = *(const half8*)(U_h + (size_t)row * N_ + kof);
                    ual = *(const half8*)(U_l + (size_t)row * N_ + kof);
                }
                #pragma unroll
                for (int j = 0; j < 2; ++j) {
                    accV[i][j] = __builtin_amdgcn_mfma_f32_16x16x32_f16(tah, bh[j], accV[i][j], 0, 0, 0);
                    accV[i][j] = __builtin_amdgcn_mfma_f32_16x16x32_f16(tal, bh[j], accV[i][j], 0, 0, 0);
                    accV[i][j] = __builtin_amdgcn_mfma_f32_16x16x32_f16(tah, bl[j], accV[i][j], 0, 0, 0);
                    accU[i][j] = __builtin_amdgcn_mfma_f32_16x16x32_f16(uah, bh[j], accU[i][j], 0, 0, 0);
                    accU[i][j] = __builtin_amdgcn_mfma_f32_16x16x32_f16(ual, bh[j], accU[i][j], 0, 0, 0);
                    accU[i][j] = __builtin_amdgcn_mfma_f32_16x16x32_f16(uah, bl[j], accU[i][j], 0, 0, 0);
                }
            }
        }
    }
    __syncthreads();  // all waves done reading T before patch overwrite

    // ---- phase 3: per-wave combine + readout ----
    float* pw = reinterpret_cast<float*>(lds_raw) + w * 2048;  // [64][32] per wave
    int c = lane & 31;
    int fh = lane >> 5;          // f-half 0/1
    int n = n0 + c;

    float y2[16];
    #pragma unroll
    for (int ff = 0; ff < 16; ++ff) y2[ff] = b2[fh * 16 + ff];

    // V2 contribution
    #pragma unroll
    for (int i = 0; i < 4; ++i)
        #pragma unroll
        for (int j = 0; j < 2; ++j)
            #pragma unroll
            for (int r = 0; r < 4; ++r)
                pw[(i * 16 + lk * 4 + r) * 32 + j * 16 + l15] = accV[i][j][r];
    #pragma unroll
    for (int ch = 0; ch < 2; ++ch) {
        float col[32];
        #pragma unroll
        for (int g = 0; g < 32; ++g) col[g] = pw[(ch * 32 + g) * 32 + c];
        #pragma unroll
        for (int ff = 0; ff < 16; ++ff) {
            const float* wr = W2 + (fh * 16 + ff) * 192 + 128 + ch * 32;
            float s = 0.f;
            #pragma unroll
            for (int g = 0; g < 32; ++g) s += wr[g] * col[g];
            y2[ff] += s;
        }
    }
    // U2 contribution (overwrite patch; wave-local, DS in-order)
    #pragma unroll
    for (int i = 0; i < 4; ++i)
        #pragma unroll
        for (int j = 0; j < 2; ++j)
            #pragma unroll
            for (int r = 0; r < 4; ++r)
                pw[(i * 16 + lk * 4 + r) * 32 + j * 16 + l15] = accU[i][j][r];
    #pragma unroll
    for (int ch = 0; ch < 2; ++ch) {
        float col[32];
        #pragma unroll
        for (int g = 0; g < 32; ++g) col[g] = pw[(ch * 32 + g) * 32 + c];
        #pragma unroll
        for (int ff = 0; ff < 16; ++ff) {
            const float* wr = W2 + (fh * 16 + ff) * 192 + 64 + ch * 32;
            float s = 0.f;
            #pragma unroll
            for (int g = 0; g < 32; ++g) s += wr[g] * col[g];
            y2[ff] += s;
        }
    }
    // Y1(t) contribution (k=0 tap), from global
    {
        const _Float16* yhc = Y1h + (size_t)bt * 64 * N_;
        const _Float16* ylc = Y1l + (size_t)bt * 64 * N_;
        #pragma unroll
        for (int ch = 0; ch < 2; ++ch) {
            float col[32];
            #pragma unroll
            for (int g = 0; g < 32; ++g) {
                size_t o = (size_t)(ch * 32 + g) * N_ + n;
                col[g] = (float)yhc[o] + (float)ylc[o];
            }
            #pragma unroll
            for (int ff = 0; ff < 16; ++ff) {
                const float* wr = W2 + (fh * 16 + ff) * 192 + ch * 32;
                float s = 0.f;
                #pragma unroll
                for (int g = 0; g < 32; ++g) s += wr[g] * col[g];
                y2[ff] += s;
            }
        }
    }
    #pragma unroll
    for (int ff = 0; ff < 16; ++ff) y2[ff] = tanh_fast(y2[ff]);

    // readout: h = tanh(A1 y2 + c1) via partner-lane join; out = A2 h + c2
    float o = 0.f;
    #pragma unroll
    for (int jj = 0; jj < 32; ++jj) {
        const float* a1 = A1 + jj * 32 + fh * 16;
        float s = 0.f;
        #pragma unroll
        for (int ff = 0; ff < 16; ++ff) s += a1[ff] * y2[ff];
        float other = __shfl_xor(s, 32, 64);
        float hj = tanh_fast(c1[jj] + s + other);
        o += A2[fh * 32 + jj] * hj;
    }
    o += c2[fh];
    out[((size_t)bt * 2 + fh) * N_ + n] = o;
}

extern "C" void kernel_launch(void* const* d_in, const int* in_sizes, int n_in,
                              void* d_out, int out_size, void* d_ws, size_t ws_size,
                              hipStream_t stream) {
    const float* x  = (const float*)d_in[0];
    const float* S  = (const float*)d_in[1];
    const float* W1 = (const float*)d_in[2];
    const float* b1 = (const float*)d_in[3];
    const float* W2 = (const float*)d_in[4];
    const float* b2 = (const float*)d_in[5];
    const float* A1 = (const float*)d_in[6];
    const float* c1 = (const float*)d_in[7];
    const float* A2 = (const float*)d_in[8];
    const float* c2 = (const float*)d_in[9];
    float* out = (float*)d_out;

    char* ws = (char*)d_ws;
    const size_t SZ_ST = (size_t)BT_ * N_ * N_ * 2;   // 67,108,864 per plane
    const size_t SZ_U1 = (size_t)BT_ * 16 * N_ * 2;   //  4,194,304 per plane
    const size_t SZ_Y1 = (size_t)BT_ * 64 * N_ * 2;   // 16,777,216 per plane
    size_t off = 0;
    _Float16* STh = (_Float16*)(ws + off); off += SZ_ST;
    _Float16* STl = (_Float16*)(ws + off); off += SZ_ST;
    _Float16* U1h = (_Float16*)(ws + off); off += SZ_U1;
    _Float16* U1l = (_Float16*)(ws + off); off += SZ_U1;
    _Float16* Y1h = (_Float16*)(ws + off); off += SZ_Y1;
    _Float16* Y1l = (_Float16*)(ws + off); off += SZ_Y1;
    if (ws_size < off) return;

    k_transpose_s<<<dim3(BT_, 4), 512, 0, stream>>>(S, STh, STl);
    k_chain1x<<<BT_, 256, 0, stream>>>(x, STh, STl, U1h, U1l);
    k_layer1b<<<BT_, 256, 0, stream>>>(U1h, U1l, STh, STl, x, W1, b1, Y1h, Y1l);
    k_layer2f<<<BT_, 512, 0, stream>>>(Y1h, Y1l, STh, STl, W2, b2, A1, c1, A2, c2, out);
}